// Round 3
// baseline (132.456 us; speedup 1.0000x reference)
//
#include <hip/hip_runtime.h>

// LengthRegulator: expanded[b,pos,:] = encoder_out[b, upper_bound(cum_dur[b], pos), :]
// for pos < min(mel_len, max_len), else 0; mel_lens[b] = cum_dur[b, T-1] (unclamped).
//
// Shapes fixed by the reference: B=16, T=512, D=384. max_len derived from out_size.
// d_out layout: [B*max_len*D floats expanded][B floats mel_lens].
//
// Two-kernel structure: (A) per-batch scan + searchsorted -> tok table in d_ws
// (sentinel -1 for zero-fill positions); (B) pure barrier-free streaming gather
// with nontemporal stores. Fallback to a fused kernel if ws is too small.

#define LR_B       16
#define LR_T       512
#define LR_D4      96          // D/4 float4s per frame (D=384)

// native clang vector type — required by __builtin_nontemporal_store
typedef float f32x4 __attribute__((ext_vector_type(4)));

// ---------------- Kernel A: scan + token table (one block per batch row) ----
__global__ __launch_bounds__(LR_T)
void lr_scan_kernel(const int* __restrict__ dur,     // [B*T]
                    int*       __restrict__ tok,     // [B*max_len] out (ws)
                    float*     __restrict__ mel_out, // [B] out (tail of d_out)
                    int max_len) {
    const int b   = blockIdx.x;
    const int tid = threadIdx.x;

    __shared__ int s_cum[LR_T];
    s_cum[tid] = dur[b * LR_T + tid];
    __syncthreads();
#pragma unroll
    for (int off = 1; off < LR_T; off <<= 1) {
        int v = (tid >= off) ? s_cum[tid - off] : 0;
        __syncthreads();
        s_cum[tid] += v;
        __syncthreads();
    }

    const int mel_raw = s_cum[LR_T - 1];
    const int mel     = min(mel_raw, max_len);
    if (tid == 0) mel_out[b] = (float)mel_raw;

    for (int pos = tid; pos < max_len; pos += LR_T) {
        int t = -1;                       // sentinel: zero-fill
        if (pos < mel) {
            int lo = 0, hi = LR_T;        // upper_bound(s_cum, pos)
            while (lo < hi) {
                int mid = (lo + hi) >> 1;
                if (s_cum[mid] <= pos) lo = mid + 1; else hi = mid;
            }
            t = min(lo, LR_T - 1);
        }
        tok[b * max_len + pos] = t;
    }
}

// ---------------- Kernel B: barrier-free streaming gather ----
#define LR_CP_THREADS 384      // 4 frames' worth of float4 lanes per iter
#define LR_CP_FRAMES  64       // frames per block

__global__ __launch_bounds__(LR_CP_THREADS)
void lr_copy_kernel(const f32x4* __restrict__ enc,   // [B*T*D4]
                    const int*   __restrict__ tok,   // [B*max_len]
                    f32x4*       __restrict__ out4,  // [B*max_len*D4]
                    int max_len) {
    const int b   = blockIdx.y;
    const int f0  = blockIdx.x * LR_CP_FRAMES;
    const int d4  = threadIdx.x % LR_D4;      // lane within frame
    const int fs  = threadIdx.x / LR_D4;      // 0..3

    const int*  tokb = tok + (size_t)b * max_len;
    const f32x4 zero = {0.f, 0.f, 0.f, 0.f};
    const size_t ob  = (size_t)b * max_len * LR_D4;
    const size_t eb  = (size_t)b * LR_T * LR_D4;

#pragma unroll
    for (int i = 0; i < LR_CP_FRAMES / 4; ++i) {
        const int f = f0 + i * 4 + fs;
        const int t = tokb[f];                 // L1-resident after first touch
        f32x4 v = zero;
        if (t >= 0) v = enc[eb + (size_t)t * LR_D4 + d4];
        __builtin_nontemporal_store(v, &out4[ob + (size_t)f * LR_D4 + d4]);
    }
}

// ---------------- Fallback: R1 fused kernel (used only if ws too small) ----
#define LR_FRAMES  64
#define LR_THREADS 512
__global__ __launch_bounds__(LR_THREADS)
void lr_fused_kernel(const float4* __restrict__ enc,
                     const int*    __restrict__ dur,
                     float*        __restrict__ out,
                     int max_len) {
    const int b    = blockIdx.y;
    const int pos0 = blockIdx.x * LR_FRAMES;
    const int tid  = threadIdx.x;

    __shared__ int s_cum[LR_T];
    __shared__ int s_tok[LR_FRAMES];

    s_cum[tid] = dur[b * LR_T + tid];
    __syncthreads();
#pragma unroll
    for (int off = 1; off < LR_T; off <<= 1) {
        int v = (tid >= off) ? s_cum[tid - off] : 0;
        __syncthreads();
        s_cum[tid] += v;
        __syncthreads();
    }
    const int mel_raw = s_cum[LR_T - 1];
    const int mel     = min(mel_raw, max_len);
    if (blockIdx.x == 0 && tid == 0)
        out[(size_t)LR_B * max_len * (LR_D4 * 4) + b] = (float)mel_raw;

    if (tid < LR_FRAMES) {
        int pos = pos0 + tid;
        int lo = 0, hi = LR_T;
        while (lo < hi) {
            int mid = (lo + hi) >> 1;
            if (s_cum[mid] <= pos) lo = mid + 1; else hi = mid;
        }
        s_tok[tid] = min(lo, LR_T - 1);
    }
    __syncthreads();

    float4* out4 = (float4*)out;
    const size_t out_base = ((size_t)b * max_len + pos0) * LR_D4;
    const float4 zero4 = make_float4(0.f, 0.f, 0.f, 0.f);
#pragma unroll
    for (int it = 0; it < (LR_FRAMES * LR_D4) / LR_THREADS; ++it) {
        int j   = it * LR_THREADS + tid;
        int f   = j / LR_D4;
        int d4  = j - f * LR_D4;
        int pos = pos0 + f;
        if (pos >= max_len) continue;
        float4 val = zero4;
        if (pos < mel) val = enc[(size_t)(b * LR_T + s_tok[f]) * LR_D4 + d4];
        out4[out_base + (size_t)f * LR_D4 + d4] = val;
    }
}

extern "C" void kernel_launch(void* const* d_in, const int* in_sizes, int n_in,
                              void* d_out, int out_size, void* d_ws, size_t ws_size,
                              hipStream_t stream) {
    const int* dur = (const int*)d_in[1];         // durations i32 [B,T]
    float*     out = (float*)d_out;

    const int max_len = (out_size - LR_B) / (LR_B * LR_D4 * 4);
    const size_t tok_bytes = (size_t)LR_B * max_len * sizeof(int);

    if (ws_size >= tok_bytes) {
        int*   tok     = (int*)d_ws;
        float* mel_out = out + (size_t)LR_B * max_len * (LR_D4 * 4);

        lr_scan_kernel<<<LR_B, LR_T, 0, stream>>>(dur, tok, mel_out, max_len);

        dim3 grid((max_len + LR_CP_FRAMES - 1) / LR_CP_FRAMES, LR_B);
        lr_copy_kernel<<<grid, LR_CP_THREADS, 0, stream>>>(
            (const f32x4*)d_in[0], tok, (f32x4*)out, max_len);
    } else {
        dim3 grid((max_len + LR_FRAMES - 1) / LR_FRAMES, LR_B);
        lr_fused_kernel<<<grid, LR_THREADS, 0, stream>>>(
            (const float4*)d_in[0], dur, out, max_len);
    }
}

// Round 4
// 129.608 us; speedup vs baseline: 1.0220x; 1.0220x over previous
//
#include <hip/hip_runtime.h>

// LengthRegulator: expanded[b,pos,:] = encoder_out[b, upper_bound(cum_dur[b], pos), :]
// for pos < min(mel_len, max_len), else 0; mel_lens[b] = cum_dur[b, T-1] (unclamped).
//
// B=16, T=512, D=384 fixed by the reference; max_len derived from out_size.
// d_out layout: [B*max_len*D floats expanded][B floats mel_lens].
//
// Single fused kernel, ZERO __syncthreads:
//  - each wave redundantly scans the 512 durations (int4x2 loads, in-register
//    prefix + 6-step __shfl_up wave scan) into a wave-PRIVATE 2 KB LDS segment
//    (in-wave LDS ordering -> no barrier needed),
//  - lanes 0..7 upper_bound their wave's 8 frames, token broadcast via __shfl,
//  - copy phase: 12 x f32x4 per lane, fully coalesced nontemporal stores.
// 8 waves/block x 4 blocks/CU = 32 waves/CU; grid = 1024 blocks = 4/CU.

#define LR_B   16
#define LR_T   512
#define LR_D4  96              // D/4 float4s per frame (D=384)

typedef float f32x4 __attribute__((ext_vector_type(4)));
typedef int   i32x4 __attribute__((ext_vector_type(4)));

__global__ __launch_bounds__(512)
void lr_kernel(const f32x4* __restrict__ enc,   // [B*T*D4]
               const int*   __restrict__ dur,   // [B*T]
               f32x4*       __restrict__ out4,  // [B*max_len*D4]
               float*       __restrict__ mel_out, // [B]
               int max_len) {
    const int b    = blockIdx.y;
    const int f0   = blockIdx.x * 64;          // first frame of this block
    const int tid  = threadIdx.x;
    const int lane = tid & 63;
    const int wid  = tid >> 6;                 // wave 0..7

    __shared__ int s_cum[8][LR_T];             // wave-private segments

    // ---- per-wave redundant scan of the 512 durations (no barriers) ----
    const i32x4* durRow = (const i32x4*)(dur + b * LR_T);
    i32x4 dA = durRow[lane * 2];
    i32x4 dB = durRow[lane * 2 + 1];
    int c0 = dA.x,      c1 = c0 + dA.y, c2 = c1 + dA.z, c3 = c2 + dA.w;
    int c4 = c3 + dB.x, c5 = c4 + dB.y, c6 = c5 + dB.z, c7 = c6 + dB.w;
    int v = c7;
#pragma unroll
    for (int off = 1; off < 64; off <<= 1) {
        int u = __shfl_up(v, off);
        if (lane >= off) v += u;
    }
    const int base = v - c7;                   // exclusive prefix of this lane's chunk
    int* seg = &s_cum[wid][0];
    i32x4 wA = {c0 + base, c1 + base, c2 + base, c3 + base};
    i32x4 wB = {c4 + base, c5 + base, c6 + base, c7 + base};
    ((i32x4*)seg)[lane * 2]     = wA;
    ((i32x4*)seg)[lane * 2 + 1] = wB;

    const int mel_raw = __shfl(v, 63);
    const int mel     = min(mel_raw, max_len);
    if (blockIdx.x == 0 && tid == 0) mel_out[b] = (float)mel_raw;

    // ---- lanes 0..7: upper_bound(cum, pos) for this wave's 8 frames ----
    int tok = -1;
    {
        const int pos = f0 + wid * 8 + lane;   // meaningful for lane < 8
        if (lane < 8 && pos < mel) {
            int lo = 0, hi = LR_T;
            while (lo < hi) {
                int mid = (lo + hi) >> 1;
                if (seg[mid] <= pos) lo = mid + 1; else hi = mid;
            }
            tok = min(lo, LR_T - 1);
        }
    }

    // ---- copy: this wave's 8 frames x 96 f32x4 = 12 per lane, coalesced ----
    const size_t eb = (size_t)b * LR_T * LR_D4;
    const size_t ob = ((size_t)b * max_len + f0 + wid * 8) * LR_D4;
    const int fbase = f0 + wid * 8;
    const f32x4 zero = {0.f, 0.f, 0.f, 0.f};
#pragma unroll
    for (int i = 0; i < 12; ++i) {
        const int e  = i * 64 + lane;          // 0..767 within this wave's span
        const int fl = e / LR_D4;              // frame 0..7 (const-div -> mul_hi)
        const int d4 = e - fl * LR_D4;
        const int t  = __shfl(tok, fl);
        f32x4 val = zero;
        if (t >= 0) val = enc[eb + (size_t)t * LR_D4 + d4];
        if (fbase + fl < max_len)              // never taken at max_len=4096
            __builtin_nontemporal_store(val, &out4[ob + e]);
    }
}

extern "C" void kernel_launch(void* const* d_in, const int* in_sizes, int n_in,
                              void* d_out, int out_size, void* d_ws, size_t ws_size,
                              hipStream_t stream) {
    const f32x4* enc = (const f32x4*)d_in[0];  // encoder_out f32 [B,T,D]
    const int*   dur = (const int*)d_in[1];    // durations i32 [B,T]
    float*       out = (float*)d_out;

    const int max_len = (out_size - LR_B) / (LR_B * LR_D4 * 4);
    float* mel_out = out + (size_t)LR_B * max_len * (LR_D4 * 4);

    dim3 grid((max_len + 63) / 64, LR_B);
    lr_kernel<<<grid, 512, 0, stream>>>(enc, dur, (f32x4*)out, mel_out, max_len);
}

// Round 5
// 125.652 us; speedup vs baseline: 1.0541x; 1.0315x over previous
//
#include <hip/hip_runtime.h>

// LengthRegulator: expanded[b,pos,:] = encoder_out[b, upper_bound(cum_dur[b], pos), :]
// for pos < min(mel_len, max_len), else 0; mel_lens[b] = cum_dur[b, T-1] (unclamped).
//
// B=16, T=512, D=384 fixed by the reference; max_len derived from out_size.
// d_out layout: [B*max_len*D floats expanded][B floats mel_lens].
//
// Single fused kernel, ZERO __syncthreads:
//  - each wave redundantly scans the 512 durations (int4x2 loads, in-register
//    prefix + 6-step __shfl_up wave scan) into a wave-PRIVATE 2 KB LDS segment
//    (in-wave LDS ordering -> no barrier needed),
//  - lanes 0..7 upper_bound their wave's 8 frames, token broadcast via __shfl,
//  - copy phase: 12 x f32x4 per lane, fully coalesced PLAIN stores
//    (R4 post-mortem: nontemporal stores appear to degrade the write stream;
//     the harness fill sustains 6.3 TB/s with plain stores),
//  - blocks entirely past mel skip LDS+search and run a pure zero-store loop.
// 8 waves/block x 4 blocks/CU = 32 waves/CU; grid = 1024 blocks = 4/CU.

#define LR_B   16
#define LR_T   512
#define LR_D4  96              // D/4 float4s per frame (D=384)

typedef float f32x4 __attribute__((ext_vector_type(4)));
typedef int   i32x4 __attribute__((ext_vector_type(4)));

__global__ __launch_bounds__(512)
void lr_kernel(const f32x4* __restrict__ enc,     // [B*T*D4]
               const int*   __restrict__ dur,     // [B*T]
               f32x4*       __restrict__ out4,    // [B*max_len*D4]
               float*       __restrict__ mel_out, // [B]
               int max_len) {
    const int b    = blockIdx.y;
    const int f0   = blockIdx.x * 64;          // first frame of this block
    const int tid  = threadIdx.x;
    const int lane = tid & 63;
    const int wid  = tid >> 6;                 // wave 0..7

    __shared__ int s_cum[8][LR_T];             // wave-private segments

    // ---- per-wave redundant scan of the 512 durations (no barriers) ----
    const i32x4* durRow = (const i32x4*)(dur + b * LR_T);
    i32x4 dA = durRow[lane * 2];
    i32x4 dB = durRow[lane * 2 + 1];
    int c0 = dA.x,      c1 = c0 + dA.y, c2 = c1 + dA.z, c3 = c2 + dA.w;
    int c4 = c3 + dB.x, c5 = c4 + dB.y, c6 = c5 + dB.z, c7 = c6 + dB.w;
    int v = c7;
#pragma unroll
    for (int off = 1; off < 64; off <<= 1) {
        int u = __shfl_up(v, off);
        if (lane >= off) v += u;
    }

    const int mel_raw = __shfl(v, 63);
    const int mel     = min(mel_raw, max_len);
    if (blockIdx.x == 0 && tid == 0) mel_out[b] = (float)mel_raw;

    const int fbase = f0 + wid * 8;            // this wave's first frame
    const size_t ob = ((size_t)b * max_len + fbase) * LR_D4;
    const f32x4 zero = {0.f, 0.f, 0.f, 0.f};

    if (fbase >= mel) {
        // ---- fully-invalid span: pure zero-store loop (no LDS, no search) ----
#pragma unroll
        for (int i = 0; i < 12; ++i)
            out4[ob + i * 64 + lane] = zero;
        return;
    }

    // ---- publish cum to wave-private LDS; lanes 0..7 upper_bound 8 frames ----
    const int base = v - c7;                   // exclusive prefix of this lane's chunk
    int* seg = &s_cum[wid][0];
    i32x4 wA = {c0 + base, c1 + base, c2 + base, c3 + base};
    i32x4 wB = {c4 + base, c5 + base, c6 + base, c7 + base};
    ((i32x4*)seg)[lane * 2]     = wA;
    ((i32x4*)seg)[lane * 2 + 1] = wB;

    int tok = -1;
    {
        const int pos = fbase + lane;          // meaningful for lane < 8
        if (lane < 8 && pos < mel) {
            int lo = 0, hi = LR_T;
            while (lo < hi) {
                int mid = (lo + hi) >> 1;
                if (seg[mid] <= pos) lo = mid + 1; else hi = mid;
            }
            tok = min(lo, LR_T - 1);
        }
    }

    // ---- copy: this wave's 8 frames x 96 f32x4 = 12 per lane, coalesced ----
    const size_t eb = (size_t)b * LR_T * LR_D4;
#pragma unroll
    for (int i = 0; i < 12; ++i) {
        const int e  = i * 64 + lane;          // 0..767 within this wave's span
        const int fl = e / LR_D4;              // frame 0..7 (const-div -> mul)
        const int d4 = e - fl * LR_D4;
        const int t  = __shfl(tok, fl);
        f32x4 val = zero;
        if (t >= 0) val = enc[eb + (size_t)t * LR_D4 + d4];
        out4[ob + e] = val;
    }
}

extern "C" void kernel_launch(void* const* d_in, const int* in_sizes, int n_in,
                              void* d_out, int out_size, void* d_ws, size_t ws_size,
                              hipStream_t stream) {
    const f32x4* enc = (const f32x4*)d_in[0];  // encoder_out f32 [B,T,D]
    const int*   dur = (const int*)d_in[1];    // durations i32 [B,T]
    float*       out = (float*)d_out;

    const int max_len = (out_size - LR_B) / (LR_B * LR_D4 * 4);
    float* mel_out = out + (size_t)LR_B * max_len * (LR_D4 * 4);

    dim3 grid((max_len + 63) / 64, LR_B);
    lr_kernel<<<grid, 512, 0, stream>>>(enc, dur, (f32x4*)out, mel_out, max_len);
}